// Round 5
// baseline (1349.248 us; speedup 1.0000x reference)
//
#include <hip/hip_runtime.h>
#include <hip/hip_bf16.h>
#include <math.h>

// Problem dims
#define B_DIM 8
#define T_DIM 4096
#define D_DIM 1024
#define H_DIM 16
#define DH_DIM 64
#define M_TOT (B_DIM * T_DIM)   // 32768
#define K_DIM 1024
#define N_DIM 1024

typedef __attribute__((ext_vector_type(8))) short short8;   // bf16x8 MFMA frag
typedef __attribute__((ext_vector_type(4))) float f32x4;    // fp32x4 acc frag

// ------------------------------------------------- split fp32 -> bf16 hi + lo
// x = hi + lo to ~17 mantissa bits (hi = bf16(x), lo = bf16(x - hi))
__global__ __launch_bounds__(256) void split_bf16_kernel(const float* __restrict__ in,
                                                         __hip_bfloat16* __restrict__ hi,
                                                         __hip_bfloat16* __restrict__ lo,
                                                         int n4) {
    int i = blockIdx.x * blockDim.x + threadIdx.x;
    int stride = gridDim.x * blockDim.x;
    for (; i < n4; i += stride) {
        float4 f = ((const float4*)in)[i];
        union { ushort4 u; __hip_bfloat16 h[4]; } ch, cl;
        #pragma unroll
        for (int j = 0; j < 4; ++j) {
            float fj = ((const float*)&f)[j];
            __hip_bfloat16 hv = __float2bfloat16(fj);
            ch.h[j] = hv;
            cl.h[j] = __float2bfloat16(fj - __bfloat162float(hv));
        }
        ((ushort4*)hi)[i] = ch.u;
        ((ushort4*)lo)[i] = cl.u;
    }
}

// ------------------------------------------------- fused dual-GEMM, split-bf16
// C[m,n] = sum_k X[m,k] * W[n,k], computed as Xh*Wh + Xh*Wl + Xl*Wh (3 MFMA).
// which==0 -> v = tanh(C + br) -> fp32 into Vout (d_out)
// which==1 -> alpha = sigmoid(C + bf) -> fp32 into Aout (ws)
#define BM 128
#define BN 128
#define BK 64

__device__ __forceinline__ void gload_lds16(const void* g, void* l) {
    __builtin_amdgcn_global_load_lds(
        (const __attribute__((address_space(1))) unsigned int*)g,
        (__attribute__((address_space(3))) unsigned int*)l,
        16, 0, 0);
}

__global__ __launch_bounds__(256) void gemm_proj_kernel(
    const __hip_bfloat16* __restrict__ Xh, const __hip_bfloat16* __restrict__ Xl,
    const __hip_bfloat16* __restrict__ WrH, const __hip_bfloat16* __restrict__ WrL,
    const __hip_bfloat16* __restrict__ WfH, const __hip_bfloat16* __restrict__ WfL,
    const float* __restrict__ br, const float* __restrict__ bfv,
    float* __restrict__ Vout,                // [M_TOT, N] fp32 (d_out)
    float* __restrict__ Aout)                // [M_TOT, N] fp32 (ws)
{
    __shared__ __align__(16) __hip_bfloat16 Ah[BM * BK];  // 16 KB each
    __shared__ __align__(16) __hip_bfloat16 Al[BM * BK];
    __shared__ __align__(16) __hip_bfloat16 Bh[BN * BK];
    __shared__ __align__(16) __hip_bfloat16 Bl[BN * BK];

    const int bm = blockIdx.x;            // 0..255
    const int which = blockIdx.y >> 3;    // 0: reach(tanh), 1: forget(sigmoid)
    const int bn = blockIdx.y & 7;        // 0..7
    const __hip_bfloat16* Wh = which ? WfH : WrH;
    const __hip_bfloat16* Wl = which ? WfL : WrL;
    const float* bias = which ? bfv : br;

    const int tid = threadIdx.x;
    const int lane = tid & 63;
    const int w = tid >> 6;               // wave 0..3
    const int wm = w >> 1, wn = w & 1;    // 2x2 wave grid, each 64x64

    f32x4 acc[4][4] = {};

    const size_t arow0 = (size_t)bm * BM;
    const size_t brow0 = (size_t)bn * BN;

    for (int kt = 0; kt < K_DIM; kt += BK) {
        __syncthreads();
        // stage the 4 tiles: each tile is 1024 16B-chunks; 256 threads x 4 iters
        #pragma unroll
        for (int i = 0; i < 4; ++i) {
            const int c = (w * 4 + i) * 64 + lane;    // wave-uniform base + lane
            const int row = c >> 3;                   // 8 chunks (128B) per row
            const int ch  = c & 7;
            const size_t ga = (arow0 + row) * K_DIM + kt + ch * 8;
            const size_t gb = (brow0 + row) * K_DIM + kt + ch * 8;
            gload_lds16(Xh + ga, &Ah[c * 8]);
            gload_lds16(Xl + ga, &Al[c * 8]);
            gload_lds16(Wh + gb, &Bh[c * 8]);
            gload_lds16(Wl + gb, &Bl[c * 8]);
        }
        __syncthreads();

        #pragma unroll
        for (int kk = 0; kk < BK; kk += 32) {
            short8 ah[4], al[4], bh[4], bl[4];
            const int koff = kk + ((lane >> 4) * 8);
            #pragma unroll
            for (int f = 0; f < 4; ++f) {
                const int ar = wm * 64 + f * 16 + (lane & 15);
                ah[f] = *(const short8*)&Ah[ar * BK + koff];
                al[f] = *(const short8*)&Al[ar * BK + koff];
                const int brr = wn * 64 + f * 16 + (lane & 15);
                bh[f] = *(const short8*)&Bh[brr * BK + koff];
                bl[f] = *(const short8*)&Bl[brr * BK + koff];
            }
            #pragma unroll
            for (int fm = 0; fm < 4; ++fm)
                #pragma unroll
                for (int fn = 0; fn < 4; ++fn) {
                    acc[fm][fn] = __builtin_amdgcn_mfma_f32_16x16x32_bf16(
                        ah[fm], bh[fn], acc[fm][fn], 0, 0, 0);
                    acc[fm][fn] = __builtin_amdgcn_mfma_f32_16x16x32_bf16(
                        ah[fm], bl[fn], acc[fm][fn], 0, 0, 0);
                    acc[fm][fn] = __builtin_amdgcn_mfma_f32_16x16x32_bf16(
                        al[fm], bh[fn], acc[fm][fn], 0, 0, 0);
                }
        }
    }

    // epilogue: C/D layout col=lane&15, row=(lane>>4)*4+reg  [m89-verified]
    const int col = lane & 15;
    const int rowb = (lane >> 4) * 4;
    #pragma unroll
    for (int fm = 0; fm < 4; ++fm) {
        #pragma unroll
        for (int fn = 0; fn < 4; ++fn) {
            const size_t gn = brow0 + wn * 64 + fn * 16 + col;
            const float bia = bias[gn];
            #pragma unroll
            for (int r = 0; r < 4; ++r) {
                const size_t gm = arow0 + wm * 64 + fm * 16 + rowb + r;
                const float val = acc[fm][fn][r] + bia;
                if (which == 0) {
                    Vout[gm * N_DIM + gn] = tanhf(val);
                } else {
                    Aout[gm * N_DIM + gn] = 1.0f / (1.0f + __expf(-val));
                }
            }
        }
    }
}

// ---------------------------------------------------------------- serial scan
// one wave (64 lanes = DH) per (b,h) chain; DPP-based 64-lane reduce
__device__ __forceinline__ float wave_sum64(float x) {
    int v;
    v = __float_as_int(x);
    x += __int_as_float(__builtin_amdgcn_update_dpp(0, v, 0x111, 0xf, 0xf, false)); // row_shr:1
    v = __float_as_int(x);
    x += __int_as_float(__builtin_amdgcn_update_dpp(0, v, 0x112, 0xf, 0xf, false)); // row_shr:2
    v = __float_as_int(x);
    x += __int_as_float(__builtin_amdgcn_update_dpp(0, v, 0x114, 0xf, 0xf, false)); // row_shr:4
    v = __float_as_int(x);
    x += __int_as_float(__builtin_amdgcn_update_dpp(0, v, 0x118, 0xf, 0xf, false)); // row_shr:8
    v = __float_as_int(x);
    x += __int_as_float(__builtin_amdgcn_update_dpp(0, v, 0x142, 0xa, 0xf, false)); // row_bcast:15
    v = __float_as_int(x);
    x += __int_as_float(__builtin_amdgcn_update_dpp(0, v, 0x143, 0xc, 0xf, false)); // row_bcast:31
    return __int_as_float(__builtin_amdgcn_readlane(__float_as_int(x), 63));
}

#define PF 8

__global__ __launch_bounds__(64) void scan_kernel(
    float* __restrict__ vout,             // d_out: v on input, final on output
    const float* __restrict__ abuf,       // alpha fp32 [M_TOT, N]
    const float* __restrict__ scale,
    const float* __restrict__ res_gate)
{
    const int bh = blockIdx.x;       // 0..127
    const int b = bh >> 4, h = bh & 15;
    const int lane = threadIdx.x;    // dh index
    const size_t base = ((size_t)b * T_DIM) * D_DIM + h * DH_DIM + lane;
    const float sc = scale[h * DH_DIM + lane];
    const float rg = res_gate[h * DH_DIM + lane];

    float state = 0.0f;
    float vc[PF], ac[PF];
    #pragma unroll
    for (int i = 0; i < PF; ++i) {
        vc[i] = vout[base + (size_t)i * D_DIM];
        ac[i] = abuf[base + (size_t)i * D_DIM];
    }

    for (int t0 = 0; t0 < T_DIM; t0 += PF) {
        float vn[PF], an[PF];
        const int t1 = t0 + PF;
        if (t1 < T_DIM) {
            #pragma unroll
            for (int i = 0; i < PF; ++i) {
                vn[i] = vout[base + (size_t)(t1 + i) * D_DIM];
                an[i] = abuf[base + (size_t)(t1 + i) * D_DIM];
            }
        } else {
            #pragma unroll
            for (int i = 0; i < PF; ++i) { vn[i] = 0.0f; an[i] = 0.0f; }
        }
        #pragma unroll
        for (int i = 0; i < PF; ++i) {
            const float a = ac[i], vv = vc[i];
            const float s = fmaf(a, state - vv, vv);      // a*state + (1-a)*v
            const float tot = wave_sum64(s * s);
            const float inv = rsqrtf(tot * (1.0f / 64.0f) + 1e-12f);
            const float f = fmaf(s * inv, sc, vv * rg);
            vout[base + (size_t)(t0 + i) * D_DIM] = f;
            state = f;
        }
        #pragma unroll
        for (int i = 0; i < PF; ++i) { vc[i] = vn[i]; ac[i] = an[i]; }
    }
}

// ---------------------------------------------------------------- launch
extern "C" void kernel_launch(void* const* d_in, const int* in_sizes, int n_in,
                              void* d_out, int out_size, void* d_ws, size_t ws_size,
                              hipStream_t stream) {
    const float* x     = (const float*)d_in[0];  // [8,4096,1024]
    const float* Wr    = (const float*)d_in[1];  // [1024,1024]
    const float* br    = (const float*)d_in[2];
    const float* Wf    = (const float*)d_in[3];
    const float* bf    = (const float*)d_in[4];
    const float* scale = (const float*)d_in[5];
    const float* rgate = (const float*)d_in[6];
    float* out = (float*)d_out;

    // ws layout (total 276,824,064 B = 264 MiB):
    //   x_hi   [ 0,          67108864)  bf16 32Mx
    //   x_lo   [ 67108864,  134217728)  bf16
    //   wr_hi  [134217728,  136314880)  bf16 1Mx
    //   wr_lo  [136314880,  138412032)
    //   wf_hi  [138412032,  140509184)
    //   wf_lo  [140509184,  142606336)
    //   alpha  [142606336,  276824064)  fp32 32Mx
    char* ws = (char*)d_ws;
    __hip_bfloat16* x_hi  = (__hip_bfloat16*)(ws);
    __hip_bfloat16* x_lo  = (__hip_bfloat16*)(ws + 67108864);
    __hip_bfloat16* wr_hi = (__hip_bfloat16*)(ws + 134217728);
    __hip_bfloat16* wr_lo = (__hip_bfloat16*)(ws + 136314880);
    __hip_bfloat16* wf_hi = (__hip_bfloat16*)(ws + 138412032);
    __hip_bfloat16* wf_lo = (__hip_bfloat16*)(ws + 140509184);
    float*          a_f32 = (float*)(ws + 142606336);

    split_bf16_kernel<<<2048, 256, 0, stream>>>(x,  x_hi,  x_lo,  (M_TOT * K_DIM) / 4);
    split_bf16_kernel<<<512,  256, 0, stream>>>(Wr, wr_hi, wr_lo, (N_DIM * K_DIM) / 4);
    split_bf16_kernel<<<512,  256, 0, stream>>>(Wf, wf_hi, wf_lo, (N_DIM * K_DIM) / 4);

    gemm_proj_kernel<<<dim3(M_TOT / BM, 16), 256, 0, stream>>>(
        x_hi, x_lo, wr_hi, wr_lo, wf_hi, wf_lo, br, bf, out, a_f32);

    scan_kernel<<<B_DIM * H_DIM, 64, 0, stream>>>(out, a_f32, scale, rgate);
}

// Round 14
// 1177.665 us; speedup vs baseline: 1.1457x; 1.1457x over previous
//
#include <hip/hip_runtime.h>
#include <hip/hip_bf16.h>
#include <math.h>

// Problem dims
#define B_DIM 8
#define T_DIM 4096
#define D_DIM 1024
#define H_DIM 16
#define DH_DIM 64
#define M_TOT (B_DIM * T_DIM)   // 32768
#define K_DIM 1024
#define N_DIM 1024
#define EPS_F 1e-12f

typedef __attribute__((ext_vector_type(8))) short short8;   // bf16x8 MFMA frag
typedef __attribute__((ext_vector_type(4))) float f32x4;    // fp32x4 acc frag

// ------------------------------------------------- split fp32 -> bf16 hi + lo
// x = hi + lo to ~17 mantissa bits (hi = bf16(x), lo = bf16(x - hi))
__global__ __launch_bounds__(256) void split_bf16_kernel(const float* __restrict__ in,
                                                         __hip_bfloat16* __restrict__ hi,
                                                         __hip_bfloat16* __restrict__ lo,
                                                         int n4) {
    int i = blockIdx.x * blockDim.x + threadIdx.x;
    int stride = gridDim.x * blockDim.x;
    for (; i < n4; i += stride) {
        float4 f = ((const float4*)in)[i];
        union { ushort4 u; __hip_bfloat16 h[4]; } ch, cl;
        #pragma unroll
        for (int j = 0; j < 4; ++j) {
            float fj = ((const float*)&f)[j];
            __hip_bfloat16 hv = __float2bfloat16(fj);
            ch.h[j] = hv;
            cl.h[j] = __float2bfloat16(fj - __bfloat162float(hv));
        }
        ((ushort4*)hi)[i] = ch.u;
        ((ushort4*)lo)[i] = cl.u;
    }
}

// ------------------------------------------------- fused dual-GEMM, split-bf16
// C[m,n] = sum_k X[m,k] * W[n,k], computed as Xh*Wh + Xh*Wl + Xl*Wh (3 MFMA).
// which==0 -> v = tanh(C + br) -> fp32 into Vout (d_out)
// which==1 -> alpha = sigmoid(C + bf) -> fp32 into Aout (ws)
#define BM 128
#define BN 128
#define BK 64

__device__ __forceinline__ void gload_lds16(const void* g, void* l) {
    __builtin_amdgcn_global_load_lds(
        (const __attribute__((address_space(1))) unsigned int*)g,
        (__attribute__((address_space(3))) unsigned int*)l,
        16, 0, 0);
}

__global__ __launch_bounds__(256) void gemm_proj_kernel(
    const __hip_bfloat16* __restrict__ Xh, const __hip_bfloat16* __restrict__ Xl,
    const __hip_bfloat16* __restrict__ WrH, const __hip_bfloat16* __restrict__ WrL,
    const __hip_bfloat16* __restrict__ WfH, const __hip_bfloat16* __restrict__ WfL,
    const float* __restrict__ br, const float* __restrict__ bfv,
    float* __restrict__ Vout,                // [M_TOT, N] fp32 (d_out)
    float* __restrict__ Aout)                // [M_TOT, N] fp32 (ws)
{
    __shared__ __align__(16) __hip_bfloat16 Ah[BM * BK];  // 16 KB each
    __shared__ __align__(16) __hip_bfloat16 Al[BM * BK];
    __shared__ __align__(16) __hip_bfloat16 Bh[BN * BK];
    __shared__ __align__(16) __hip_bfloat16 Bl[BN * BK];

    // grid remap: consecutive block ids share the same X-tile (bm), walking
    // all 16 W-panels -> X-tile reused 16x by near-co-resident blocks (L2).
    // Pure bijective index permutation; numerics identical.
    const int bid = blockIdx.x;           // 0..4095
    const int bm = bid >> 4;              // 0..255  (X row-tile)
    const int py = bid & 15;              // 0..15   (W panel)
    const int which = py >> 3;            // 0: reach(tanh), 1: forget(sigmoid)
    const int bn = py & 7;                // 0..7
    const __hip_bfloat16* Wh = which ? WfH : WrH;
    const __hip_bfloat16* Wl = which ? WfL : WrL;
    const float* bias = which ? bfv : br;

    const int tid = threadIdx.x;
    const int lane = tid & 63;
    const int w = tid >> 6;               // wave 0..3
    const int wm = w >> 1, wn = w & 1;    // 2x2 wave grid, each 64x64

    f32x4 acc[4][4] = {};

    const size_t arow0 = (size_t)bm * BM;
    const size_t brow0 = (size_t)bn * BN;

    for (int kt = 0; kt < K_DIM; kt += BK) {
        __syncthreads();
        // stage the 4 tiles: each tile is 1024 16B-chunks; 256 threads x 4 iters
        #pragma unroll
        for (int i = 0; i < 4; ++i) {
            const int c = (w * 4 + i) * 64 + lane;    // wave-uniform base + lane
            const int row = c >> 3;                   // 8 chunks (128B) per row
            const int ch  = c & 7;
            const size_t ga = (arow0 + row) * K_DIM + kt + ch * 8;
            const size_t gb = (brow0 + row) * K_DIM + kt + ch * 8;
            gload_lds16(Xh + ga, &Ah[c * 8]);
            gload_lds16(Xl + ga, &Al[c * 8]);
            gload_lds16(Wh + gb, &Bh[c * 8]);
            gload_lds16(Wl + gb, &Bl[c * 8]);
        }
        __syncthreads();

        #pragma unroll
        for (int kk = 0; kk < BK; kk += 32) {
            short8 ah[4], al[4], bh[4], bl[4];
            const int koff = kk + ((lane >> 4) * 8);
            #pragma unroll
            for (int f = 0; f < 4; ++f) {
                const int ar = wm * 64 + f * 16 + (lane & 15);
                ah[f] = *(const short8*)&Ah[ar * BK + koff];
                al[f] = *(const short8*)&Al[ar * BK + koff];
                const int brr = wn * 64 + f * 16 + (lane & 15);
                bh[f] = *(const short8*)&Bh[brr * BK + koff];
                bl[f] = *(const short8*)&Bl[brr * BK + koff];
            }
            #pragma unroll
            for (int fm = 0; fm < 4; ++fm)
                #pragma unroll
                for (int fn = 0; fn < 4; ++fn) {
                    acc[fm][fn] = __builtin_amdgcn_mfma_f32_16x16x32_bf16(
                        ah[fm], bh[fn], acc[fm][fn], 0, 0, 0);
                    acc[fm][fn] = __builtin_amdgcn_mfma_f32_16x16x32_bf16(
                        ah[fm], bl[fn], acc[fm][fn], 0, 0, 0);
                    acc[fm][fn] = __builtin_amdgcn_mfma_f32_16x16x32_bf16(
                        al[fm], bh[fn], acc[fm][fn], 0, 0, 0);
                }
        }
    }

    // epilogue: C/D layout col=lane&15, row=(lane>>4)*4+reg  [m89-verified]
    const int col = lane & 15;
    const int rowb = (lane >> 4) * 4;
    #pragma unroll
    for (int fm = 0; fm < 4; ++fm) {
        #pragma unroll
        for (int fn = 0; fn < 4; ++fn) {
            const size_t gn = brow0 + wn * 64 + fn * 16 + col;
            const float bia = bias[gn];
            #pragma unroll
            for (int r = 0; r < 4; ++r) {
                const size_t gm = arow0 + wm * 64 + fm * 16 + rowb + r;
                const float val = acc[fm][fn][r] + bia;
                if (which == 0) {
                    Vout[gm * N_DIM + gn] = tanhf(val);
                } else {
                    Aout[gm * N_DIM + gn] = 1.0f / (1.0f + __expf(-val));
                }
            }
        }
    }
}

// ---------------------------------------------------------------- serial scan
// one wave (64 lanes = DH) per (b,h) chain.
// Butterfly 64-lane sum, result broadcast to ALL lanes (no readlane round-trip).
// CTRL must be a compile-time constant -> template parameter (r12 compile fix).
template<int CTRL>
__device__ __forceinline__ float dpp_add(float x) {
    return x + __int_as_float(__builtin_amdgcn_update_dpp(
        0, __float_as_int(x), CTRL, 0xf, 0xf, false));
}

__device__ __forceinline__ float bfly_sum64(float x) {
    x = dpp_add<0xB1>(x);    // quad_perm [1,0,3,2]  : + lane^1
    x = dpp_add<0x4E>(x);    // quad_perm [2,3,0,1]  : + lane^2
    x = dpp_add<0x141>(x);   // row_half_mirror      : + cross-4 within 8
    x = dpp_add<0x140>(x);   // row_mirror           : + cross-8 within 16
#if __has_builtin(__builtin_amdgcn_permlane16_swap) && __has_builtin(__builtin_amdgcn_permlane32_swap)
    {
        unsigned int xu = __float_as_uint(x);
        auto r16 = __builtin_amdgcn_permlane16_swap(xu, xu, false, false);
        x = __uint_as_float(r16[0]) + __uint_as_float(r16[1]);   // cross-16
        unsigned int yu = __float_as_uint(x);
        auto r32 = __builtin_amdgcn_permlane32_swap(yu, yu, false, false);
        x = __uint_as_float(r32[0]) + __uint_as_float(r32[1]);   // cross-32
        return x;
    }
#else
    {
        // fallback: bcast chain leaves total in lane 63, broadcast via readlane
        int v = __float_as_int(x);
        x += __int_as_float(__builtin_amdgcn_update_dpp(0, v, 0x142, 0xa, 0xf, false)); // row_bcast:15
        v = __float_as_int(x);
        x += __int_as_float(__builtin_amdgcn_update_dpp(0, v, 0x143, 0xc, 0xf, false)); // row_bcast:31
        return __int_as_float(__builtin_amdgcn_readlane(__float_as_int(x), 63));
    }
#endif
}

#define PF 16

// Recurrence in normalized form sigma = s/8 (8 = sqrt(DH)):
//   g_t   = a_t * scale                          (off critical path)
//   ctil  = (a_t*(v_{t-1}*rg - v_t) + v_t)/8     (off critical path)
//   sigma_t = inv_{t-1} * (g_t * sigma_{t-1}) + ctil
//   inv_t = rsqrt(sum(sigma_t^2) + EPS)
//   f_t   = inv_t * (sigma_t * 8*scale) + v_t*rg
// Loop-carried chain: inv -> fma -> square -> 6 bfly adds -> +eps -> rsq  (~10 ops)
__global__ __launch_bounds__(64) void scan_kernel(
    float* __restrict__ vout,             // d_out: v on input, final on output
    const float* __restrict__ abuf,       // alpha fp32 [M_TOT, N]
    const float* __restrict__ scale,
    const float* __restrict__ res_gate)
{
    const int bh = blockIdx.x;       // 0..127
    const int b = bh >> 4, h = bh & 15;
    const int lane = threadIdx.x;    // dh index
    const size_t base = ((size_t)b * T_DIM) * D_DIM + h * DH_DIM + lane;
    const float sc = scale[h * DH_DIM + lane];
    const float rg = res_gate[h * DH_DIM + lane];
    const float sc8 = 8.0f * sc;

    float sig = 0.0f;      // sigma_{t-1}
    float inv = 0.0f;      // inv_{t-1} (t=0: multiplied by p=0, value irrelevant)
    float wprev = 0.0f;    // v_{t-1} * rg (t=0: state_{-1}=0)

    float vc[PF], ac[PF];
    #pragma unroll
    for (int i = 0; i < PF; ++i) {
        vc[i] = vout[base + (size_t)i * D_DIM];
        ac[i] = abuf[base + (size_t)i * D_DIM];
    }

    for (int t0 = 0; t0 < T_DIM; t0 += PF) {
        float vn[PF], an[PF];
        const int t1 = t0 + PF;
        if (t1 < T_DIM) {
            #pragma unroll
            for (int i = 0; i < PF; ++i) {
                vn[i] = vout[base + (size_t)(t1 + i) * D_DIM];
                an[i] = abuf[base + (size_t)(t1 + i) * D_DIM];
            }
        } else {
            #pragma unroll
            for (int i = 0; i < PF; ++i) { vn[i] = 0.0f; an[i] = 0.0f; }
        }
        #pragma unroll
        for (int i = 0; i < PF; ++i) {
            const float a  = ac[i], vv = vc[i];
            const float g  = a * sc;                            // off-path
            const float cc = fmaf(a, wprev - vv, vv) * 0.125f;  // off-path
            wprev = vv * rg;                                    // w_t (off-path)
            const float p  = g * sig;                           // off inv-path
            sig = fmaf(inv, p, cc);                             // sigma_t
            const float T  = bfly_sum64(sig * sig);             // 7 dep ops
            inv = __builtin_amdgcn_rsqf(T + EPS_F);             // inv_t
            const float f  = fmaf(inv, sig * sc8, wprev);       // output (off-path)
            vout[base + (size_t)(t0 + i) * D_DIM] = f;
        }
        #pragma unroll
        for (int i = 0; i < PF; ++i) { vc[i] = vn[i]; ac[i] = an[i]; }
    }
}

// ---------------------------------------------------------------- launch
extern "C" void kernel_launch(void* const* d_in, const int* in_sizes, int n_in,
                              void* d_out, int out_size, void* d_ws, size_t ws_size,
                              hipStream_t stream) {
    const float* x     = (const float*)d_in[0];  // [8,4096,1024]
    const float* Wr    = (const float*)d_in[1];  // [1024,1024]
    const float* br    = (const float*)d_in[2];
    const float* Wf    = (const float*)d_in[3];
    const float* bf    = (const float*)d_in[4];
    const float* scale = (const float*)d_in[5];
    const float* rgate = (const float*)d_in[6];
    float* out = (float*)d_out;

    // ws layout (total 276,824,064 B = 264 MiB):
    char* ws = (char*)d_ws;
    __hip_bfloat16* x_hi  = (__hip_bfloat16*)(ws);
    __hip_bfloat16* x_lo  = (__hip_bfloat16*)(ws + 67108864);
    __hip_bfloat16* wr_hi = (__hip_bfloat16*)(ws + 134217728);
    __hip_bfloat16* wr_lo = (__hip_bfloat16*)(ws + 136314880);
    __hip_bfloat16* wf_hi = (__hip_bfloat16*)(ws + 138412032);
    __hip_bfloat16* wf_lo = (__hip_bfloat16*)(ws + 140509184);
    float*          a_f32 = (float*)(ws + 142606336);

    split_bf16_kernel<<<2048, 256, 0, stream>>>(x,  x_hi,  x_lo,  (M_TOT * K_DIM) / 4);
    split_bf16_kernel<<<512,  256, 0, stream>>>(Wr, wr_hi, wr_lo, (N_DIM * K_DIM) / 4);
    split_bf16_kernel<<<512,  256, 0, stream>>>(Wf, wf_hi, wf_lo, (N_DIM * K_DIM) / 4);

    gemm_proj_kernel<<<4096, 256, 0, stream>>>(
        x_hi, x_lo, wr_hi, wr_lo, wf_hi, wf_lo, br, bf, out, a_f32);

    scan_kernel<<<B_DIM * H_DIM, 64, 0, stream>>>(out, a_f32, scale, rgate);
}

// Round 16
// 1005.970 us; speedup vs baseline: 1.3412x; 1.1707x over previous
//
#include <hip/hip_runtime.h>
#include <hip/hip_bf16.h>
#include <math.h>

// Problem dims
#define B_DIM 8
#define T_DIM 4096
#define D_DIM 1024
#define H_DIM 16
#define DH_DIM 64
#define M_TOT (B_DIM * T_DIM)   // 32768
#define K_DIM 1024
#define N_DIM 1024
#define EPS_F 1e-12f

typedef __attribute__((ext_vector_type(8))) short short8;   // bf16x8 MFMA frag
typedef __attribute__((ext_vector_type(4))) float f32x4;    // fp32x4 acc frag

// ------------------------------------------------- split fp32 -> bf16 hi + lo
// x = hi + lo to ~17 mantissa bits (hi = bf16(x), lo = bf16(x - hi))
__global__ __launch_bounds__(256) void split_bf16_kernel(const float* __restrict__ in,
                                                         __hip_bfloat16* __restrict__ hi,
                                                         __hip_bfloat16* __restrict__ lo,
                                                         int n4) {
    int i = blockIdx.x * blockDim.x + threadIdx.x;
    int stride = gridDim.x * blockDim.x;
    for (; i < n4; i += stride) {
        float4 f = ((const float4*)in)[i];
        union { ushort4 u; __hip_bfloat16 h[4]; } ch, cl;
        #pragma unroll
        for (int j = 0; j < 4; ++j) {
            float fj = ((const float*)&f)[j];
            __hip_bfloat16 hv = __float2bfloat16(fj);
            ch.h[j] = hv;
            cl.h[j] = __float2bfloat16(fj - __bfloat162float(hv));
        }
        ((ushort4*)hi)[i] = ch.u;
        ((ushort4*)lo)[i] = cl.u;
    }
}

// ------------------------------------------------- fused dual-GEMM, split-bf16
// C[m,n] = sum_k X[m,k] * W[n,k], computed as Xh*Wh + Xh*Wl + Xl*Wh (3 MFMA).
// which==0 -> v = tanh(C + br) -> fp32 into Vout (d_out)
// which==1 -> alpha = sigmoid(C + bf) -> fp32 into Aout (ws)
#define BM 128
#define BN 128
#define BK 64

__device__ __forceinline__ void gload_lds16(const void* g, void* l) {
    __builtin_amdgcn_global_load_lds(
        (const __attribute__((address_space(1))) unsigned int*)g,
        (__attribute__((address_space(3))) unsigned int*)l,
        16, 0, 0);
}

__global__ __launch_bounds__(256) void gemm_proj_kernel(
    const __hip_bfloat16* __restrict__ Xh, const __hip_bfloat16* __restrict__ Xl,
    const __hip_bfloat16* __restrict__ WrH, const __hip_bfloat16* __restrict__ WrL,
    const __hip_bfloat16* __restrict__ WfH, const __hip_bfloat16* __restrict__ WfL,
    const float* __restrict__ br, const float* __restrict__ bfv,
    float* __restrict__ Vout,                // [M_TOT, N] fp32 (d_out)
    float* __restrict__ Aout)                // [M_TOT, N] fp32 (ws)
{
    __shared__ __align__(16) __hip_bfloat16 Ah[BM * BK];  // 16 KB each
    __shared__ __align__(16) __hip_bfloat16 Al[BM * BK];
    __shared__ __align__(16) __hip_bfloat16 Bh[BN * BK];
    __shared__ __align__(16) __hip_bfloat16 Bl[BN * BK];

    // grid remap: consecutive block ids share the same X-tile (bm), walking
    // all 16 W-panels -> X-tile reused 16x by near-co-resident blocks (L2).
    const int bid = blockIdx.x;           // 0..4095
    const int bm = bid >> 4;              // 0..255  (X row-tile)
    const int py = bid & 15;              // 0..15   (W panel)
    const int which = py >> 3;            // 0: reach(tanh), 1: forget(sigmoid)
    const int bn = py & 7;                // 0..7
    const __hip_bfloat16* Wh = which ? WfH : WrH;
    const __hip_bfloat16* Wl = which ? WfL : WrL;
    const float* bias = which ? bfv : br;

    const int tid = threadIdx.x;
    const int lane = tid & 63;
    const int w = tid >> 6;               // wave 0..3
    const int wm = w >> 1, wn = w & 1;    // 2x2 wave grid, each 64x64

    f32x4 acc[4][4] = {};

    const size_t arow0 = (size_t)bm * BM;
    const size_t brow0 = (size_t)bn * BN;

    for (int kt = 0; kt < K_DIM; kt += BK) {
        __syncthreads();
        // stage the 4 tiles: each tile is 1024 16B-chunks; 256 threads x 4 iters
        #pragma unroll
        for (int i = 0; i < 4; ++i) {
            const int c = (w * 4 + i) * 64 + lane;    // wave-uniform base + lane
            const int row = c >> 3;                   // 8 chunks (128B) per row
            const int ch  = c & 7;
            const size_t ga = (arow0 + row) * K_DIM + kt + ch * 8;
            const size_t gb = (brow0 + row) * K_DIM + kt + ch * 8;
            gload_lds16(Xh + ga, &Ah[c * 8]);
            gload_lds16(Xl + ga, &Al[c * 8]);
            gload_lds16(Wh + gb, &Bh[c * 8]);
            gload_lds16(Wl + gb, &Bl[c * 8]);
        }
        __syncthreads();

        #pragma unroll
        for (int kk = 0; kk < BK; kk += 32) {
            short8 ah[4], al[4], bh[4], bl[4];
            const int koff = kk + ((lane >> 4) * 8);
            #pragma unroll
            for (int f = 0; f < 4; ++f) {
                const int ar = wm * 64 + f * 16 + (lane & 15);
                ah[f] = *(const short8*)&Ah[ar * BK + koff];
                al[f] = *(const short8*)&Al[ar * BK + koff];
                const int brr = wn * 64 + f * 16 + (lane & 15);
                bh[f] = *(const short8*)&Bh[brr * BK + koff];
                bl[f] = *(const short8*)&Bl[brr * BK + koff];
            }
            #pragma unroll
            for (int fm = 0; fm < 4; ++fm)
                #pragma unroll
                for (int fn = 0; fn < 4; ++fn) {
                    acc[fm][fn] = __builtin_amdgcn_mfma_f32_16x16x32_bf16(
                        ah[fm], bh[fn], acc[fm][fn], 0, 0, 0);
                    acc[fm][fn] = __builtin_amdgcn_mfma_f32_16x16x32_bf16(
                        ah[fm], bl[fn], acc[fm][fn], 0, 0, 0);
                    acc[fm][fn] = __builtin_amdgcn_mfma_f32_16x16x32_bf16(
                        al[fm], bh[fn], acc[fm][fn], 0, 0, 0);
                }
        }
    }

    // epilogue: C/D layout col=lane&15, row=(lane>>4)*4+reg  [m89-verified]
    const int col = lane & 15;
    const int rowb = (lane >> 4) * 4;
    #pragma unroll
    for (int fm = 0; fm < 4; ++fm) {
        #pragma unroll
        for (int fn = 0; fn < 4; ++fn) {
            const size_t gn = brow0 + wn * 64 + fn * 16 + col;
            const float bia = bias[gn];
            #pragma unroll
            for (int r = 0; r < 4; ++r) {
                const size_t gm = arow0 + wm * 64 + fm * 16 + rowb + r;
                const float val = acc[fm][fn][r] + bia;
                if (which == 0) {
                    Vout[gm * N_DIM + gn] = tanhf(val);
                } else {
                    Aout[gm * N_DIM + gn] = 1.0f / (1.0f + __expf(-val));
                }
            }
        }
    }
}

// ---------------------------------------------------------------- serial scan
// one wave (64 lanes = DH) per (b,h) chain.
template<int CTRL>
__device__ __forceinline__ float dpp_add(float x) {
    return x + __int_as_float(__builtin_amdgcn_update_dpp(
        0, __float_as_int(x), CTRL, 0xf, 0xf, false));
}

__device__ __forceinline__ float bfly_sum64(float x) {
    x = dpp_add<0xB1>(x);    // quad_perm [1,0,3,2]  : + lane^1
    x = dpp_add<0x4E>(x);    // quad_perm [2,3,0,1]  : + lane^2
    x = dpp_add<0x141>(x);   // row_half_mirror      : + cross-4 within 8
    x = dpp_add<0x140>(x);   // row_mirror           : + cross-8 within 16
#if __has_builtin(__builtin_amdgcn_permlane16_swap) && __has_builtin(__builtin_amdgcn_permlane32_swap)
    {
        unsigned int xu = __float_as_uint(x);
        auto r16 = __builtin_amdgcn_permlane16_swap(xu, xu, false, false);
        x = __uint_as_float(r16[0]) + __uint_as_float(r16[1]);   // cross-16
        unsigned int yu = __float_as_uint(x);
        auto r32 = __builtin_amdgcn_permlane32_swap(yu, yu, false, false);
        x = __uint_as_float(r32[0]) + __uint_as_float(r32[1]);   // cross-32
        return x;
    }
#else
    {
        int v = __float_as_int(x);
        x += __int_as_float(__builtin_amdgcn_update_dpp(0, v, 0x142, 0xa, 0xf, false)); // row_bcast:15
        v = __float_as_int(x);
        x += __int_as_float(__builtin_amdgcn_update_dpp(0, v, 0x143, 0xc, 0xf, false)); // row_bcast:31
        return __int_as_float(__builtin_amdgcn_readlane(__float_as_int(x), 63));
    }
#endif
}

#define PF 16

// Inline-asm load: compiler cannot sink it or eliminate the dest register.
// Result valid only after the explicit counted s_waitcnt below (r14 fix:
// VGPR=40 proved the C++-level double buffer was DCE'd -> loads sank to uses
// -> ~250 cy/step exposed memory latency).
#define GLOAD(dst, ptr) asm volatile("global_load_dword %0, %1, off" \
    : "=v"(dst) : "v"(ptr) : "memory")

// One scan step (normalized recurrence, r14-verified numerics).
#define SCAN_STEP(a_, v_, tidx) do { \
    const float a  = (a_), vv = (v_); \
    const float g  = a * sc; \
    const float cc = fmaf(a, wprev - vv, vv) * 0.125f; \
    wprev = vv * rg; \
    const float p  = g * sig; \
    sig = fmaf(inv, p, cc); \
    const float Tt = bfly_sum64(sig * sig); \
    inv = __builtin_amdgcn_rsqf(Tt + EPS_F); \
    vout[base + (size_t)(tidx) * D_DIM] = fmaf(inv, sig * sc8, wprev); \
} while (0)

__global__ __launch_bounds__(64) void scan_kernel(
    float* __restrict__ vout,             // d_out: v on input, final on output
    const float* __restrict__ abuf,       // alpha fp32 [M_TOT, N]
    const float* __restrict__ scale,
    const float* __restrict__ res_gate)
{
    const int bh = blockIdx.x;       // 0..127
    const int b = bh >> 4, h = bh & 15;
    const int lane = threadIdx.x;    // dh index
    const size_t base = ((size_t)b * T_DIM) * D_DIM + h * DH_DIM + lane;
    const float sc = scale[h * DH_DIM + lane];
    const float rg = res_gate[h * DH_DIM + lane];
    const float sc8 = 8.0f * sc;

    float sig = 0.0f, inv = 0.0f, wprev = 0.0f;

    float vA[PF], aA[PF], vB[PF], aB[PF];

    // prologue: load block 0 into A, wait all
    #pragma unroll
    for (int i = 0; i < PF; ++i) {
        GLOAD(vA[i], vout + base + (size_t)i * D_DIM);
        GLOAD(aA[i], abuf + base + (size_t)i * D_DIM);
    }
    asm volatile("s_waitcnt vmcnt(0)" ::: "memory");
    __builtin_amdgcn_sched_barrier(0);

    for (int t0 = 0; t0 < T_DIM; t0 += 2 * PF) {
        // ---- body A: prefetch block t0+PF into B, compute block t0 from A
        {
            const int tn = t0 + PF;      // 16..4080, always in range
            #pragma unroll
            for (int i = 0; i < PF; ++i) {
                GLOAD(vB[i], vout + base + (size_t)(tn + i) * D_DIM);
                GLOAD(aB[i], abuf + base + (size_t)(tn + i) * D_DIM);
            }
            #pragma unroll
            for (int i = 0; i < PF; ++i) SCAN_STEP(aA[i], vA[i], t0 + i);
            // 32 loads + 16 stores outstanding; allow the 16 newest (stores)
            asm volatile("s_waitcnt vmcnt(16)" ::: "memory");
            __builtin_amdgcn_sched_barrier(0);
        }
        // ---- body B: prefetch block t0+2*PF into A, compute block t0+PF from B
        {
            const int tn = t0 + 2 * PF;  // last block clamps (dummy loads)
            #pragma unroll
            for (int i = 0; i < PF; ++i) {
                const int t = (tn + i < T_DIM) ? (tn + i) : (T_DIM - 1);
                GLOAD(vA[i], vout + base + (size_t)t * D_DIM);
                GLOAD(aA[i], abuf + base + (size_t)t * D_DIM);
            }
            #pragma unroll
            for (int i = 0; i < PF; ++i) SCAN_STEP(aB[i], vB[i], t0 + PF + i);
            asm volatile("s_waitcnt vmcnt(16)" ::: "memory");
            __builtin_amdgcn_sched_barrier(0);
        }
    }
}

// ---------------------------------------------------------------- launch
extern "C" void kernel_launch(void* const* d_in, const int* in_sizes, int n_in,
                              void* d_out, int out_size, void* d_ws, size_t ws_size,
                              hipStream_t stream) {
    const float* x     = (const float*)d_in[0];  // [8,4096,1024]
    const float* Wr    = (const float*)d_in[1];  // [1024,1024]
    const float* br    = (const float*)d_in[2];
    const float* Wf    = (const float*)d_in[3];
    const float* bf    = (const float*)d_in[4];
    const float* scale = (const float*)d_in[5];
    const float* rgate = (const float*)d_in[6];
    float* out = (float*)d_out;

    // ws layout (total 276,824,064 B = 264 MiB):
    char* ws = (char*)d_ws;
    __hip_bfloat16* x_hi  = (__hip_bfloat16*)(ws);
    __hip_bfloat16* x_lo  = (__hip_bfloat16*)(ws + 67108864);
    __hip_bfloat16* wr_hi = (__hip_bfloat16*)(ws + 134217728);
    __hip_bfloat16* wr_lo = (__hip_bfloat16*)(ws + 136314880);
    __hip_bfloat16* wf_hi = (__hip_bfloat16*)(ws + 138412032);
    __hip_bfloat16* wf_lo = (__hip_bfloat16*)(ws + 140509184);
    float*          a_f32 = (float*)(ws + 142606336);

    split_bf16_kernel<<<2048, 256, 0, stream>>>(x,  x_hi,  x_lo,  (M_TOT * K_DIM) / 4);
    split_bf16_kernel<<<512,  256, 0, stream>>>(Wr, wr_hi, wr_lo, (N_DIM * K_DIM) / 4);
    split_bf16_kernel<<<512,  256, 0, stream>>>(Wf, wf_hi, wf_lo, (N_DIM * K_DIM) / 4);

    gemm_proj_kernel<<<4096, 256, 0, stream>>>(
        x_hi, x_lo, wr_hi, wr_lo, wf_hi, wf_lo, br, bf, out, a_f32);

    scan_kernel<<<B_DIM * H_DIM, 64, 0, stream>>>(out, a_f32, scale, rgate);
}